// Round 1
// baseline (2597.622 us; speedup 1.0000x reference)
//
#include <hip/hip_runtime.h>

#define N_NODES 200000
#define N_EDGES 800000
#define N_RULES 50000
#define NLAYERS 24
#define SCAN_NB 196        // ceil(200000/1024)
#define RP_STRIDE 200064   // ints per rp array (padded)

typedef short bf16x8 __attribute__((ext_vector_type(8)));
typedef float floatx4 __attribute__((ext_vector_type(4)));

__device__ __forceinline__ unsigned short f2bf(float f) {
  unsigned int b = __float_as_uint(f);
  b += 0x7FFFu + ((b >> 16) & 1u);          // round-to-nearest-even
  return (unsigned short)(b >> 16);
}

// ---------------- CSR build ----------------

__global__ void k_hist(const int* __restrict__ src, const int* __restrict__ tgt,
                       int* __restrict__ deg_out, int* __restrict__ deg_back) {
  int e = blockIdx.x * 256 + threadIdx.x;   // E = 3125*256 exact
  atomicAdd(&deg_out[tgt[e]], 1);
  atomicAdd(&deg_back[src[e]], 1);
}

__global__ void k_scanA(const int* __restrict__ deg, int* __restrict__ part) {
  int y = blockIdx.y;
  const int* d = deg + y * N_NODES;
  __shared__ int sh[256];
  int t = threadIdx.x;
  int base = blockIdx.x * 1024 + t * 4;
  int s = 0;
  #pragma unroll
  for (int k = 0; k < 4; ++k) { int i = base + k; if (i < N_NODES) s += d[i]; }
  sh[t] = s; __syncthreads();
  for (int off = 128; off > 0; off >>= 1) { if (t < off) sh[t] += sh[t + off]; __syncthreads(); }
  if (t == 0) part[y * SCAN_NB + blockIdx.x] = sh[0];
}

__global__ void k_scanB(int* __restrict__ part, int* __restrict__ rp) {
  int y = blockIdx.y;
  __shared__ int buf[256];
  int t = threadIdx.x;
  int v = (t < SCAN_NB) ? part[y * SCAN_NB + t] : 0;
  buf[t] = v; __syncthreads();
  for (int off = 1; off < 256; off <<= 1) {
    int x = (t >= off) ? buf[t - off] : 0;
    __syncthreads();
    buf[t] += x;
    __syncthreads();
  }
  if (t < SCAN_NB) part[y * SCAN_NB + t] = buf[t] - v;   // exclusive
  if (t == 0) rp[y * RP_STRIDE + N_NODES] = N_EDGES;
}

__global__ void k_scanC(const int* __restrict__ deg, const int* __restrict__ part,
                        int* __restrict__ rp) {
  int y = blockIdx.y;
  const int* d = deg + y * N_NODES;
  int* r = rp + y * RP_STRIDE;
  __shared__ int buf[256];
  int t = threadIdx.x;
  int base = blockIdx.x * 1024 + t * 4;
  int dv[4]; int s = 0;
  #pragma unroll
  for (int k = 0; k < 4; ++k) { int i = base + k; dv[k] = (i < N_NODES) ? d[i] : 0; s += dv[k]; }
  buf[t] = s; __syncthreads();
  int sv = s;
  for (int off = 1; off < 256; off <<= 1) {
    int x = (t >= off) ? buf[t - off] : 0;
    __syncthreads();
    buf[t] += x;
    __syncthreads();
  }
  int e = part[y * SCAN_NB + blockIdx.x] + buf[t] - sv;
  #pragma unroll
  for (int k = 0; k < 4; ++k) { int i = base + k; if (i < N_NODES) r[i] = e; e += dv[k]; }
}

__global__ void k_fill(const int* __restrict__ src, const int* __restrict__ tgt,
                       const int* __restrict__ rp_out, const int* __restrict__ rp_back,
                       int* __restrict__ cur_out, int* __restrict__ cur_back,
                       int* __restrict__ ci_out, int* __restrict__ ci_back) {
  int e = blockIdx.x * 256 + threadIdx.x;
  int s = src[e], t = tgt[e];
  int p = rp_out[t] + atomicAdd(&cur_out[t], 1);
  ci_out[p] = s;
  int q = rp_back[s] + atomicAdd(&cur_back[s], 1);
  ci_back[q] = t;
}

// ---------------- BN-folded weight prep (bf16 MFMA A-fragments) ----------------
// W'[c][j] = W[c][j]*s[j],  b'[c] = b[c] + sum_j W[c][j]*(beta[j]-rmean[j]*s[j])
// Fragment f = ct*2+kh: element (lane, jj) = W'[ct*16+(lane&15)][kh*32+(lane>>4)*8+jj]
__global__ void k_prep(const float* __restrict__ W, const float* __restrict__ b,
                       const float* __restrict__ gamma, const float* __restrict__ beta,
                       const float* __restrict__ rmean, const float* __restrict__ rvar,
                       unsigned short* __restrict__ WpF, float* __restrict__ bp) {
  int d = blockIdx.x, l = blockIdx.y, lane = threadIdx.x;
  int ld = l * 2 + d;
  __shared__ float s_s[64], t_s[64];
  float s = gamma[ld * 64 + lane] * rsqrtf(rvar[ld * 64 + lane] + 1e-5f);
  s_s[lane] = s;
  t_s[lane] = beta[ld * 64 + lane] - rmean[ld * 64 + lane] * s;
  __syncthreads();
  float bias = b[ld * 64 + lane];
  for (int j = 0; j < 64; ++j) bias += W[(ld * 64 + lane) * 64 + j] * t_s[j];
  bp[ld * 64 + lane] = bias;
  #pragma unroll
  for (int f = 0; f < 8; ++f) {
    int ct = f >> 1, kh = f & 1;
    int row = ct * 16 + (lane & 15);
    #pragma unroll
    for (int jj = 0; jj < 8; ++jj) {
      int k = kh * 32 + (lane >> 4) * 8 + jj;
      float val = W[(ld * 64 + row) * 64 + k] * s_s[k];
      WpF[(ld * 8 + f) * 512 + lane * 8 + jj] = f2bf(val);
    }
  }
}

// ---------------- embedding gather ----------------
__global__ void k_embed(const int* __restrict__ nodes, const float* __restrict__ emb,
                        float* __restrict__ x) {
  int gid = blockIdx.x * 256 + threadIdx.x;     // N*64 = 50000*256 exact
  int i = gid >> 6, c = gid & 63;
  x[gid] = emb[nodes[i] * 64 + c];
}

// ---------------- fused layer: gather-mean (both dirs) + BN-folded matvec (MFMA) + residual ----
// 1 wave = 16 consecutive nodes; grid 3125 blocks * 4 waves = 12500 groups exact.
__global__ __launch_bounds__(256) void k_layer(
    const float* __restrict__ x_in, float* __restrict__ x_out,
    const int* __restrict__ rp0, const int* __restrict__ ci0,
    const int* __restrict__ rp1, const int* __restrict__ ci1,
    const unsigned short* __restrict__ WfL, const float* __restrict__ bpL) {
  __shared__ __align__(16) unsigned short m_s[4][16 * 72];  // bf16, pitch 72
  __shared__ __align__(16) float y_s[4][16 * 68];           // f32, pitch 68
  __shared__ float bp_s[128];
  __shared__ int rp_s[4][18];
  int tid = threadIdx.x, lane = tid & 63, w = tid >> 6;
  if (tid < 128) bp_s[tid] = bpL[tid];
  __syncthreads();
  int base = (blockIdx.x * 4 + w) * 16;
  int n15 = lane & 15, q = lane >> 4;

  for (int d = 0; d < 2; ++d) {
    const int* rp = d ? rp1 : rp0;
    const int* ci = d ? ci1 : ci0;
    if (lane < 17) rp_s[w][lane] = rp[base + lane];
    int rs = rp_s[w][0], re = rp_s[w][16];
    int cur = 0;
    int cstart = rs;
    int cend = rp_s[w][1];
    float acc = 0.f;
    for (int cb = rs; cb < re; cb += 64) {
      int ce = (cb + 64 < re) ? cb + 64 : re;
      int cv = 0;
      if (cb + lane < re) cv = ci[cb + lane];
      for (int j0 = cb; j0 < ce; j0 += 8) {
        float v[8];
        #pragma unroll
        for (int u = 0; u < 8; ++u) {
          int srcn = __shfl(cv, j0 + u - cb);
          v[u] = (j0 + u < ce) ? x_in[srcn * 64 + lane] : 0.f;
        }
        #pragma unroll
        for (int u = 0; u < 8; ++u) {
          int j = j0 + u;
          if (j < ce) {
            while (j >= cend) {            // flush node `cur`
              int deg = cend - cstart;
              float invc = deg > 0 ? 1.f / (float)deg : 0.f;
              m_s[w][cur * 72 + lane] = f2bf(acc * invc);
              acc = 0.f; cur++;
              cstart = cend; cend = rp_s[w][cur + 1];
            }
            acc += v[u];
          }
        }
      }
    }
    while (cur < 16) {                     // trailing flush
      int nend = rp_s[w][cur + 1];
      int deg = nend - cstart;
      float invc = deg > 0 ? 1.f / (float)deg : 0.f;
      m_s[w][cur * 72 + lane] = f2bf(acc * invc);
      acc = 0.f; cstart = nend; cur++;
    }

    // MFMA: y[64ch x 16node] = W' @ m ; A-frags from global (register-resident), B from LDS
    const unsigned short* wf = WfL + d * 4096;
    bf16x8 b0 = *(const bf16x8*)&m_s[w][n15 * 72 + 0 + q * 8];
    bf16x8 b1 = *(const bf16x8*)&m_s[w][n15 * 72 + 32 + q * 8];
    #pragma unroll
    for (int ct = 0; ct < 4; ++ct) {
      floatx4 a4 = {0.f, 0.f, 0.f, 0.f};
      bf16x8 a0 = *(const bf16x8*)(wf + (ct * 2 + 0) * 512 + lane * 8);
      bf16x8 a1 = *(const bf16x8*)(wf + (ct * 2 + 1) * 512 + lane * 8);
      a4 = __builtin_amdgcn_mfma_f32_16x16x32_bf16(a0, b0, a4, 0, 0, 0);
      a4 = __builtin_amdgcn_mfma_f32_16x16x32_bf16(a1, b1, a4, 0, 0, 0);
      // D: col = lane&15 = node, row = ct*16 + q*4 + i = channel
      float4 yv;
      yv.x = fmaxf(a4[0] + bp_s[d * 64 + ct * 16 + q * 4 + 0], 0.f);
      yv.y = fmaxf(a4[1] + bp_s[d * 64 + ct * 16 + q * 4 + 1], 0.f);
      yv.z = fmaxf(a4[2] + bp_s[d * 64 + ct * 16 + q * 4 + 2], 0.f);
      yv.w = fmaxf(a4[3] + bp_s[d * 64 + ct * 16 + q * 4 + 3], 0.f);
      float* yp = &y_s[w][n15 * 68 + ct * 16 + q * 4];
      if (d == 0) {
        *(float4*)yp = yv;
      } else {
        float4 o = *(const float4*)yp;
        o.x += yv.x; o.y += yv.y; o.z += yv.z; o.w += yv.w;
        *(float4*)yp = o;
      }
    }
  }

  #pragma unroll
  for (int r = 0; r < 16; ++r)
    x_out[(base + r) * 64 + lane] = x_in[(base + r) * 64 + lane] + y_s[w][r * 68 + lane];
}

// ---------------- readout: out[r] = Wo . relu(Wh @ x[rules[r]] + bh) ----------------
__global__ __launch_bounds__(256) void k_final(
    const float* __restrict__ x, const int* __restrict__ rules,
    const float* __restrict__ Wh, const float* __restrict__ bh,
    const float* __restrict__ Wo, float* __restrict__ out) {
  __shared__ float v_s[4][16][64];
  int tid = threadIdx.x, lane = tid & 63, w = tid >> 6;
  int rbase = (blockIdx.x * 4 + w) * 16;
  #pragma unroll
  for (int r = 0; r < 16; ++r) {
    int ru = rbase + r;
    int nd = (ru < N_RULES) ? rules[ru] : 0;
    v_s[w][r][lane] = x[nd * 64 + lane];
  }
  float acc[16];
  #pragma unroll
  for (int r = 0; r < 16; ++r) acc[r] = 0.f;
  for (int jb = 0; jb < 16; ++jb) {
    int j = jb * 64 + lane;
    float wo = Wo[j];
    float bhj = bh[j];
    float h[16];
    #pragma unroll
    for (int r = 0; r < 16; ++r) h[r] = bhj;
    #pragma unroll 4
    for (int k4 = 0; k4 < 16; ++k4) {
      float4 w4 = *(const float4*)&Wh[j * 64 + k4 * 4];
      #pragma unroll
      for (int r = 0; r < 16; ++r) {
        float4 v4 = *(const float4*)&v_s[w][r][k4 * 4];
        h[r] += w4.x * v4.x + w4.y * v4.y + w4.z * v4.z + w4.w * v4.w;
      }
    }
    #pragma unroll
    for (int r = 0; r < 16; ++r) acc[r] += fmaxf(h[r], 0.f) * wo;
  }
  #pragma unroll
  for (int r = 0; r < 16; ++r) {
    float a = acc[r];
    #pragma unroll
    for (int off = 32; off > 0; off >>= 1) a += __shfl_down(a, off);
    if (lane == 0 && rbase + r < N_RULES) out[rbase + r] = a;
  }
}

// ---------------- launch ----------------
extern "C" void kernel_launch(void* const* d_in, const int* in_sizes, int n_in,
                              void* d_out, int out_size, void* d_ws, size_t ws_size,
                              hipStream_t stream) {
  const int* nodes = (const int*)d_in[0];
  const int* sources = (const int*)d_in[1];
  const int* targets = (const int*)d_in[2];
  const int* rules = (const int*)d_in[3];
  const float* emb = (const float*)d_in[4];
  const float* W = (const float*)d_in[5];
  const float* b = (const float*)d_in[6];
  const float* gamma = (const float*)d_in[7];
  const float* beta = (const float*)d_in[8];
  const float* rmean = (const float*)d_in[9];
  const float* rvar = (const float*)d_in[10];
  const float* Wh = (const float*)d_in[11];
  const float* bh = (const float*)d_in[12];
  const float* Wo = (const float*)d_in[13];
  float* out = (float*)d_out;

  if (ws_size < 115000000u) return;  // need ~114 MB scratch

  char* ws = (char*)d_ws;
  float* x_a = (float*)(ws + 0);                      // 51.2 MB
  float* x_b = (float*)(ws + 51200000);               // 51.2 MB
  int* deg_out = (int*)(ws + 102400000);              // 800 KB
  // deg_back = deg_out + N (contiguous)
  int* cur_out = (int*)(ws + 104000000);              // 800 KB
  int* cur_back = (int*)(ws + 104800000);             // 800 KB
  int* rp_out = (int*)(ws + 105600000);               // stride RP_STRIDE ints, x2
  int* rp_back = rp_out + RP_STRIDE;
  int* ci_out = (int*)(ws + 107200512);               // 3.2 MB
  int* ci_back = (int*)(ws + 110400512);              // 3.2 MB
  int* part = (int*)(ws + 113600512);                 // 2*196 ints
  unsigned short* WpF = (unsigned short*)(ws + 113602560);  // 384 KB
  float* bp = (float*)(ws + 113995776);               // 12 KB
  int* deg_back = deg_out + N_NODES;

  // zero deg_out, deg_back, cur_out, cur_back (contiguous 3.2 MB)
  hipMemsetAsync(deg_out, 0, 4u * 800000u, stream);

  k_hist<<<3125, 256, 0, stream>>>(sources, targets, deg_out, deg_back);
  k_scanA<<<dim3(SCAN_NB, 2), 256, 0, stream>>>(deg_out, part);
  k_scanB<<<dim3(1, 2), 256, 0, stream>>>(part, rp_out);
  k_scanC<<<dim3(SCAN_NB, 2), 256, 0, stream>>>(deg_out, part, rp_out);
  k_fill<<<3125, 256, 0, stream>>>(sources, targets, rp_out, rp_back,
                                   cur_out, cur_back, ci_out, ci_back);
  k_prep<<<dim3(2, NLAYERS), 64, 0, stream>>>(W, b, gamma, beta, rmean, rvar, WpF, bp);
  k_embed<<<50000, 256, 0, stream>>>(nodes, emb, x_a);

  float* xi = x_a;
  float* xo = x_b;
  for (int l = 0; l < NLAYERS; ++l) {
    k_layer<<<3125, 256, 0, stream>>>(xi, xo, rp_out, ci_out, rp_back, ci_back,
                                      WpF + (size_t)l * 8192, bp + (size_t)l * 128);
    float* t = xi; xi = xo; xo = t;
  }
  k_final<<<782, 256, 0, stream>>>(xi, rules, Wh, bh, Wo, out);
}

// Round 2
// 2093.411 us; speedup vs baseline: 1.2409x; 1.2409x over previous
//
#include <hip/hip_runtime.h>

#define N_NODES 200000
#define N_EDGES 800000
#define N_RULES 50000
#define NLAYERS 24
#define SCAN_NB 196        // ceil(200000/1024)
#define RP_STRIDE 200064   // ints per rp array (padded)

typedef short bf16x8 __attribute__((ext_vector_type(8)));
typedef float floatx4 __attribute__((ext_vector_type(4)));

__device__ __forceinline__ unsigned short f2bf(float f) {
  unsigned int b = __float_as_uint(f);
  b += 0x7FFFu + ((b >> 16) & 1u);          // round-to-nearest-even
  return (unsigned short)(b >> 16);
}
__device__ __forceinline__ float bf2f(unsigned short u) {
  return __uint_as_float(((unsigned int)u) << 16);
}

// ---------------- CSR build ----------------

__global__ void k_hist(const int* __restrict__ src, const int* __restrict__ tgt,
                       int* __restrict__ deg_out, int* __restrict__ deg_back) {
  int e = blockIdx.x * 256 + threadIdx.x;   // E = 3125*256 exact
  atomicAdd(&deg_out[tgt[e]], 1);
  atomicAdd(&deg_back[src[e]], 1);
}

__global__ void k_scanA(const int* __restrict__ deg, int* __restrict__ part) {
  int y = blockIdx.y;
  const int* d = deg + y * N_NODES;
  __shared__ int sh[256];
  int t = threadIdx.x;
  int base = blockIdx.x * 1024 + t * 4;
  int s = 0;
  #pragma unroll
  for (int k = 0; k < 4; ++k) { int i = base + k; if (i < N_NODES) s += d[i]; }
  sh[t] = s; __syncthreads();
  for (int off = 128; off > 0; off >>= 1) { if (t < off) sh[t] += sh[t + off]; __syncthreads(); }
  if (t == 0) part[y * SCAN_NB + blockIdx.x] = sh[0];
}

__global__ void k_scanB(int* __restrict__ part, int* __restrict__ rp) {
  int y = blockIdx.y;
  __shared__ int buf[256];
  int t = threadIdx.x;
  int v = (t < SCAN_NB) ? part[y * SCAN_NB + t] : 0;
  buf[t] = v; __syncthreads();
  for (int off = 1; off < 256; off <<= 1) {
    int x = (t >= off) ? buf[t - off] : 0;
    __syncthreads();
    buf[t] += x;
    __syncthreads();
  }
  if (t < SCAN_NB) part[y * SCAN_NB + t] = buf[t] - v;   // exclusive
  if (t == 0) rp[y * RP_STRIDE + N_NODES] = N_EDGES;
}

__global__ void k_scanC(const int* __restrict__ deg, const int* __restrict__ part,
                        int* __restrict__ rp) {
  int y = blockIdx.y;
  const int* d = deg + y * N_NODES;
  int* r = rp + y * RP_STRIDE;
  __shared__ int buf[256];
  int t = threadIdx.x;
  int base = blockIdx.x * 1024 + t * 4;
  int dv[4]; int s = 0;
  #pragma unroll
  for (int k = 0; k < 4; ++k) { int i = base + k; dv[k] = (i < N_NODES) ? d[i] : 0; s += dv[k]; }
  buf[t] = s; __syncthreads();
  int sv = s;
  for (int off = 1; off < 256; off <<= 1) {
    int x = (t >= off) ? buf[t - off] : 0;
    __syncthreads();
    buf[t] += x;
    __syncthreads();
  }
  int e = part[y * SCAN_NB + blockIdx.x] + buf[t] - sv;
  #pragma unroll
  for (int k = 0; k < 4; ++k) { int i = base + k; if (i < N_NODES) r[i] = e; e += dv[k]; }
}

__global__ void k_fill(const int* __restrict__ src, const int* __restrict__ tgt,
                       const int* __restrict__ rp_out, const int* __restrict__ rp_back,
                       int* __restrict__ cur_out, int* __restrict__ cur_back,
                       int* __restrict__ ci_out, int* __restrict__ ci_back) {
  int e = blockIdx.x * 256 + threadIdx.x;
  int s = src[e], t = tgt[e];
  int p = rp_out[t] + atomicAdd(&cur_out[t], 1);
  ci_out[p] = s;
  int q = rp_back[s] + atomicAdd(&cur_back[s], 1);
  ci_back[q] = t;
}

// ---------------- BN-folded weight prep (bf16 MFMA A-fragments) ----------------
__global__ void k_prep(const float* __restrict__ W, const float* __restrict__ b,
                       const float* __restrict__ gamma, const float* __restrict__ beta,
                       const float* __restrict__ rmean, const float* __restrict__ rvar,
                       unsigned short* __restrict__ WpF, float* __restrict__ bp) {
  int d = blockIdx.x, l = blockIdx.y, lane = threadIdx.x;
  int ld = l * 2 + d;
  __shared__ float s_s[64], t_s[64];
  float s = gamma[ld * 64 + lane] * rsqrtf(rvar[ld * 64 + lane] + 1e-5f);
  s_s[lane] = s;
  t_s[lane] = beta[ld * 64 + lane] - rmean[ld * 64 + lane] * s;
  __syncthreads();
  float bias = b[ld * 64 + lane];
  for (int j = 0; j < 64; ++j) bias += W[(ld * 64 + lane) * 64 + j] * t_s[j];
  bp[ld * 64 + lane] = bias;
  #pragma unroll
  for (int f = 0; f < 8; ++f) {
    int ct = f >> 1, kh = f & 1;
    int row = ct * 16 + (lane & 15);
    #pragma unroll
    for (int jj = 0; jj < 8; ++jj) {
      int k = kh * 32 + (lane >> 4) * 8 + jj;
      float val = W[(ld * 64 + row) * 64 + k] * s_s[k];
      WpF[(ld * 8 + f) * 512 + lane * 8 + jj] = f2bf(val);
    }
  }
}

// ---------------- embedding gather (fp32 master + bf16 shadow) ----------------
__global__ void k_embed(const int* __restrict__ nodes, const float* __restrict__ emb,
                        float* __restrict__ x, unsigned short* __restrict__ xbf) {
  int gid = blockIdx.x * 256 + threadIdx.x;     // N*64 = 50000*256 exact
  int i = gid >> 6, c = gid & 63;
  float v = emb[nodes[i] * 64 + c];
  x[gid] = v;
  xbf[gid] = f2bf(v);
}

// ---------------- fused layer ----------------
// gather-mean from bf16 shadow (both dirs) + BN-folded matvec (MFMA) + in-place
// fp32 residual + bf16 shadow write. 1 wave = 16 consecutive nodes.
__global__ __launch_bounds__(256) void k_layer(
    float* __restrict__ x,                         // fp32 master, updated in place
    const unsigned short* __restrict__ xbf_in,     // bf16 shadow of x (input gen)
    unsigned short* __restrict__ xbf_out,          // bf16 shadow of x (output gen)
    const int* __restrict__ rp0, const int* __restrict__ ci0,
    const int* __restrict__ rp1, const int* __restrict__ ci1,
    const unsigned short* __restrict__ WfL, const float* __restrict__ bpL) {
  __shared__ __align__(16) unsigned short m_s[4][16 * 72];  // bf16, pitch 72
  __shared__ __align__(16) float y_s[4][16 * 68];           // f32, pitch 68
  __shared__ float bp_s[128];
  __shared__ int rp_s[4][18];
  int tid = threadIdx.x, lane = tid & 63, w = tid >> 6;
  if (tid < 128) bp_s[tid] = bpL[tid];
  __syncthreads();
  int base = (blockIdx.x * 4 + w) * 16;
  int n15 = lane & 15, q = lane >> 4;

  for (int d = 0; d < 2; ++d) {
    const int* rp = d ? rp1 : rp0;
    const int* ci = d ? ci1 : ci0;
    if (lane < 17) rp_s[w][lane] = rp[base + lane];
    int rs = __builtin_amdgcn_readfirstlane(rp_s[w][0]);
    int re = __builtin_amdgcn_readfirstlane(rp_s[w][16]);
    int cur = 0;
    int cstart = rs;
    int cend = __builtin_amdgcn_readfirstlane(rp_s[w][1]);
    float acc = 0.f;
    for (int cb = rs; cb < re; cb += 64) {
      int ce = (cb + 64 < re) ? cb + 64 : re;
      int cv = (cb + lane < re) ? ci[cb + lane] : 0;  // coalesced edge-index chunk
      for (int j0 = cb; j0 < ce; j0 += 8) {
        float v[8];
        #pragma unroll
        for (int u = 0; u < 8; ++u) {
          // broadcast edge source via v_readlane (VALU, no LDS pipe)
          int sn = __builtin_amdgcn_readlane(cv, j0 + u - cb);
          v[u] = bf2f(xbf_in[sn * 64 + lane]);        // 128B/row bf16 gather
        }
        #pragma unroll
        for (int u = 0; u < 8; ++u) {
          int j = j0 + u;
          if (j < ce) {                                // scalar branch
            while (j >= cend) {                        // flush node `cur`
              int deg = cend - cstart;
              float invc = deg > 0 ? 1.f / (float)deg : 0.f;
              m_s[w][cur * 72 + lane] = f2bf(acc * invc);
              acc = 0.f; cur++;
              cstart = cend;
              cend = __builtin_amdgcn_readfirstlane(rp_s[w][cur + 1]);
            }
            acc += v[u];
          }
        }
      }
    }
    #pragma unroll 1
    while (cur < 16) {                                 // trailing flush
      int deg = cend - cstart;
      float invc = deg > 0 ? 1.f / (float)deg : 0.f;
      m_s[w][cur * 72 + lane] = f2bf(acc * invc);
      acc = 0.f; cstart = cend; cur++;
      if (cur < 16) cend = __builtin_amdgcn_readfirstlane(rp_s[w][cur + 1]);
    }

    // MFMA: y[64ch x 16node] = W' @ m ; A-frags register-resident from global
    const unsigned short* wf = WfL + d * 4096;
    bf16x8 b0 = *(const bf16x8*)&m_s[w][n15 * 72 + 0 + q * 8];
    bf16x8 b1 = *(const bf16x8*)&m_s[w][n15 * 72 + 32 + q * 8];
    #pragma unroll
    for (int ct = 0; ct < 4; ++ct) {
      floatx4 a4 = {0.f, 0.f, 0.f, 0.f};
      bf16x8 a0 = *(const bf16x8*)(wf + (ct * 2 + 0) * 512 + lane * 8);
      bf16x8 a1 = *(const bf16x8*)(wf + (ct * 2 + 1) * 512 + lane * 8);
      a4 = __builtin_amdgcn_mfma_f32_16x16x32_bf16(a0, b0, a4, 0, 0, 0);
      a4 = __builtin_amdgcn_mfma_f32_16x16x32_bf16(a1, b1, a4, 0, 0, 0);
      // D: col = lane&15 = node, row = ct*16 + q*4 + i = channel
      floatx4 yv;
      #pragma unroll
      for (int i = 0; i < 4; ++i)
        yv[i] = fmaxf(a4[i] + bp_s[d * 64 + ct * 16 + q * 4 + i], 0.f);
      float* yp = &y_s[w][n15 * 68 + ct * 16 + q * 4];
      if (d == 0) {
        *(floatx4*)yp = yv;
      } else {
        floatx4 o = *(const floatx4*)yp;
        o += yv;
        *(floatx4*)yp = o;
      }
    }
  }

  #pragma unroll
  for (int r = 0; r < 16; ++r) {
    int gi = (base + r) * 64 + lane;
    float xv = x[gi] + y_s[w][r * 68 + lane];
    x[gi] = xv;                  // in-place: only this block touches these rows
    xbf_out[gi] = f2bf(xv);
  }
}

// ---------------- readout: out[r] = Wo . relu(Wh @ x[rules[r]] + bh) ----------------
// register-blocked fp32: 4 hidden units per lane -> 16 FMAs per LDS broadcast read
__global__ __launch_bounds__(256) void k_final(
    const float* __restrict__ x, const int* __restrict__ rules,
    const float* __restrict__ Wh, const float* __restrict__ bh,
    const float* __restrict__ Wo, float* __restrict__ out) {
  __shared__ __align__(16) float v_s[4][16][64];
  int tid = threadIdx.x, lane = tid & 63, w = tid >> 6;
  int rbase = (blockIdx.x * 4 + w) * 16;
  #pragma unroll
  for (int r = 0; r < 16; ++r) {
    int ru = rbase + r;
    int nd = (ru < N_RULES) ? rules[ru] : 0;
    v_s[w][r][lane] = x[nd * 64 + lane];
  }
  float acc[16];
  #pragma unroll
  for (int r = 0; r < 16; ++r) acc[r] = 0.f;
  for (int jb = 0; jb < 4; ++jb) {
    int j0 = jb * 256 + lane * 4;                 // this lane's 4 hidden units
    floatx4 bh4 = *(const floatx4*)&bh[j0];
    floatx4 wo4 = *(const floatx4*)&Wo[j0];
    float h[4][16];
    #pragma unroll
    for (int jj = 0; jj < 4; ++jj)
      #pragma unroll
      for (int r = 0; r < 16; ++r) h[jj][r] = bh4[jj];
    for (int k4 = 0; k4 < 16; ++k4) {
      floatx4 wr[4];
      #pragma unroll
      for (int jj = 0; jj < 4; ++jj)
        wr[jj] = *(const floatx4*)&Wh[(j0 + jj) * 64 + k4 * 4];
      #pragma unroll
      for (int r = 0; r < 16; ++r) {
        floatx4 v4 = *(const floatx4*)&v_s[w][r][k4 * 4];  // wave-uniform broadcast
        #pragma unroll
        for (int jj = 0; jj < 4; ++jj)
          h[jj][r] += wr[jj][0]*v4[0] + wr[jj][1]*v4[1] + wr[jj][2]*v4[2] + wr[jj][3]*v4[3];
      }
    }
    #pragma unroll
    for (int r = 0; r < 16; ++r) {
      float s = fmaxf(h[0][r], 0.f) * wo4[0] + fmaxf(h[1][r], 0.f) * wo4[1]
              + fmaxf(h[2][r], 0.f) * wo4[2] + fmaxf(h[3][r], 0.f) * wo4[3];
      acc[r] += s;
    }
  }
  #pragma unroll
  for (int r = 0; r < 16; ++r) {
    float a = acc[r];
    #pragma unroll
    for (int off = 32; off > 0; off >>= 1) a += __shfl_down(a, off);
    if (lane == 0 && rbase + r < N_RULES) out[rbase + r] = a;
  }
}

// ---------------- launch ----------------
extern "C" void kernel_launch(void* const* d_in, const int* in_sizes, int n_in,
                              void* d_out, int out_size, void* d_ws, size_t ws_size,
                              hipStream_t stream) {
  const int* nodes = (const int*)d_in[0];
  const int* sources = (const int*)d_in[1];
  const int* targets = (const int*)d_in[2];
  const int* rules = (const int*)d_in[3];
  const float* emb = (const float*)d_in[4];
  const float* W = (const float*)d_in[5];
  const float* b = (const float*)d_in[6];
  const float* gamma = (const float*)d_in[7];
  const float* beta = (const float*)d_in[8];
  const float* rmean = (const float*)d_in[9];
  const float* rvar = (const float*)d_in[10];
  const float* Wh = (const float*)d_in[11];
  const float* bh = (const float*)d_in[12];
  const float* Wo = (const float*)d_in[13];
  float* out = (float*)d_out;

  if (ws_size < 114500000u) return;  // need ~114 MB scratch

  char* ws = (char*)d_ws;
  float* x = (float*)(ws + 0);                              // 51.2 MB fp32 master
  unsigned short* xbf_a = (unsigned short*)(ws + 51200000); // 25.6 MB bf16 shadow
  unsigned short* xbf_b = (unsigned short*)(ws + 76800000); // 25.6 MB bf16 shadow
  int* deg_out = (int*)(ws + 102400000);                    // 800 KB
  int* deg_back = deg_out + N_NODES;                        // 800 KB
  int* cur_out = (int*)(ws + 104000000);                    // 800 KB
  int* cur_back = (int*)(ws + 104800000);                   // 800 KB
  int* rp_out = (int*)(ws + 105600000);                     // 2 x RP_STRIDE ints
  int* rp_back = rp_out + RP_STRIDE;
  int* ci_out = (int*)(ws + 107200512);                     // 3.2 MB
  int* ci_back = (int*)(ws + 110400512);                    // 3.2 MB
  int* part = (int*)(ws + 113600512);                       // 1568 B
  unsigned short* WpF = (unsigned short*)(ws + 113602096);  // 384 KB (16B aligned)
  float* bp = (float*)(ws + 113995312);                     // 12 KB

  // zero deg_out/deg_back/cur_out/cur_back (contiguous 3.2 MB)
  hipMemsetAsync(deg_out, 0, 3200000u, stream);

  k_hist<<<3125, 256, 0, stream>>>(sources, targets, deg_out, deg_back);
  k_scanA<<<dim3(SCAN_NB, 2), 256, 0, stream>>>(deg_out, part);
  k_scanB<<<dim3(1, 2), 256, 0, stream>>>(part, rp_out);
  k_scanC<<<dim3(SCAN_NB, 2), 256, 0, stream>>>(deg_out, part, rp_out);
  k_fill<<<3125, 256, 0, stream>>>(sources, targets, rp_out, rp_back,
                                   cur_out, cur_back, ci_out, ci_back);
  k_prep<<<dim3(2, NLAYERS), 64, 0, stream>>>(W, b, gamma, beta, rmean, rvar, WpF, bp);
  k_embed<<<50000, 256, 0, stream>>>(nodes, emb, x, xbf_a);

  const unsigned short* bi = xbf_a;
  unsigned short* bo = xbf_b;
  for (int l = 0; l < NLAYERS; ++l) {
    k_layer<<<3125, 256, 0, stream>>>(x, bi, bo, rp_out, ci_out, rp_back, ci_back,
                                      WpF + (size_t)l * 8192, bp + (size_t)l * 128);
    const unsigned short* t = bi; bi = bo; bo = (unsigned short*)t;
  }
  k_final<<<782, 256, 0, stream>>>(x, rules, Wh, bh, Wo, out);
}